// Round 10
// baseline (5028.461 us; speedup 1.0000x reference)
//
#include <hip/hip_runtime.h>

typedef unsigned short u16;
typedef unsigned int   u32;
typedef unsigned long long u64;
typedef signed char    i8;
typedef __attribute__((ext_vector_type(4))) int  i32x4;
typedef __attribute__((ext_vector_type(2))) long i64x2;

// ---------------- problem constants ----------------
#define NSTEP 512

// ---------------- workspace layout (bytes) ----------------
#define OFF_QX8   0ull
#define SZ_QX8    (32768ull*512)            // x quantized, int8
#define OFF_QWT8  (OFF_QX8 + SZ_QX8)
#define SZ_QT8    (1536ull*512)             // W^T / R^T quantized, int8
#define OFF_QRT8  (OFF_QWT8 + SZ_QT8)
#define OFF_QWX2  (OFF_QRT8 + SZ_QT8)
#define SZ_QWX2   (512ull*4*512*4*3*4)      // Wx gate-packed dwords
#define OFF_QBX   (OFF_QWX2 + SZ_QWX2)      // 1536 int
#define OFF_QBR   (OFF_QBX + 6144)          // 1536 int
#define OFF_LUT   (OFF_QBR + 6144)          // 256 int sigmoid + 256 int tanh
#define OFF_RING  (OFF_LUT + 2048)          // 2 slots x 8 wg-images x 2048 u32
#define RING_WORDS (2*8*2048)
#define SZ_RING   (RING_WORDS*4ull)
#define WS_NEED   (OFF_RING + SZ_RING)

// ---------------- helpers ----------------
__device__ __forceinline__ int iclip8(int v){ return v < -128 ? -128 : (v > 127 ? 127 : v); }

// round-half-even of (v / 2^k) for integer v (matches jnp.round on exact values)
__device__ __forceinline__ int rhe(int v, int k){
  int b = v >> k;
  int r = v & ((1 << k) - 1);
  int half = 1 << (k - 1);
  return b + ((r > half) || (r == half && (b & 1)));
}

__device__ __forceinline__ int qi8(float x, float s){
  float q = rintf(x * s);
  q = fminf(fmaxf(q, -128.f), 127.f);
  return (int)q;
}

// MFMA i8 wrapper: tolerate either i32x4- or i64x2-typed builtin signature.
template<typename V>
__device__ __forceinline__ auto mfma_i8_try(V a, V b, i32x4 c, int)
  -> decltype(__builtin_amdgcn_mfma_i32_16x16x64_i8(a, b, c, 0, 0, 0)) {
  return __builtin_amdgcn_mfma_i32_16x16x64_i8(a, b, c, 0, 0, 0);
}
template<typename V>
__device__ __forceinline__ i32x4 mfma_i8_try(V a, V b, i32x4 c, long) {
  return __builtin_amdgcn_mfma_i32_16x16x64_i8(
      __builtin_bit_cast(i64x2, a), __builtin_bit_cast(i64x2, b), c, 0, 0, 0);
}
__device__ __forceinline__ i32x4 mfma_i8(i32x4 a, i32x4 b, i32x4 c){
  return mfma_i8_try(a, b, c, 0);
}

// LLC-coherent (bypass L1+L2) store/zero — the PROVEN exchange fabric
__device__ __forceinline__ void st_llc(u32* p, u32 v){
  asm volatile("global_store_dword %0, %1, off sc0 sc1" :: "v"((u64)p), "v"(v) : "memory");
}
__device__ __forceinline__ void llc_zero16(u32* p){
  i32x4 z = {0,0,0,0};
  asm volatile("global_store_dwordx4 %0, %1, off sc0 sc1" :: "v"((u64)p), "v"(z) : "memory");
}

// ---------------- phase 0: quantization / tables ----------------
__global__ void k0a_qx(const float* __restrict__ x, u32* __restrict__ qx8, int n4){
  int i = blockIdx.x * blockDim.x + threadIdx.x;
  int st = gridDim.x * blockDim.x;
  for (; i < n4; i += st) {
    float4 v = ((const float4*)x)[i];
    u32 b0 = (u32)(qi8(v.x, 16.f) & 0xFF);
    u32 b1 = (u32)(qi8(v.y, 16.f) & 0xFF);
    u32 b2 = (u32)(qi8(v.z, 16.f) & 0xFF);
    u32 b3 = (u32)(qi8(v.w, 16.f) & 0xFF);
    qx8[i] = b0 | (b1 << 8) | (b2 << 16) | (b3 << 24);
  }
}

__global__ void k0b_qwr(const float* __restrict__ W, const float* __restrict__ Rm,
                        i8* __restrict__ qwT8, i8* __restrict__ qrT8){
  int idx = blockIdx.x * 256 + threadIdx.x;       // 0 .. 2*786432-1
  if (idx >= 2*786432) return;
  int m = idx >= 786432;
  int rem = idx - m * 786432;                     // = k*1536 + n (coalesced read)
  int k = rem / 1536;
  int n = rem - k * 1536;
  const float* s = m ? Rm : W;
  i8* d = m ? qrT8 : qwT8;
  d[n*512 + k] = (i8)qi8(s[rem], 1024.f);
}

__global__ void k0c_misc(const float* __restrict__ bx, const float* __restrict__ br,
                         int* __restrict__ qbx, int* __restrict__ qbr,
                         int* __restrict__ lut, u32* __restrict__ ring){
  int i = blockIdx.x * 256 + threadIdx.x;         // 4096 threads
  if (i < 1536) {
    qbx[i] = iclip8((int)rintf(bx[i] * 256.f));
    qbr[i] = iclip8((int)rintf(br[i] * 256.f));
  }
  if (i < 256) {
    double v = (i - 128) * 0.125;                 // all possible pre-activations
    float sg = (float)(1.0 / (1.0 + exp(-v)));
    int qs = (int)rintf(sg * 256.f);
    lut[i] = qs < 0 ? 0 : (qs > 255 ? 255 : qs);
    float th = (float)tanh(v);
    lut[256 + i] = iclip8((int)rintf(th * 128.f));
  }
  // zero the ring EVERY launch via LLC stores: tags >=1, so no leftover matches
  llc_zero16(ring + i*8);
  llc_zero16(ring + i*8 + 4);
}

// ---------------- phase 1: Wx = fq(xq @ Wq, 4), gate-packed dwords ----------
// (R6-verbatim, absmax=0 proven) dword at (((t*4+bgrp)*512+hcol)*4+g)*3+gate
// packs batch rows bgrp*16 + 4g + 0..3.
__global__ __launch_bounds__(256) void k1_gemm_wx(const i8* __restrict__ qx8,
                                                  const i8* __restrict__ qwT8,
                                                  u32* __restrict__ qwx2){
  __shared__ i8 xs[128][80];
  __shared__ i8 ws[128][80];
  int bid = blockIdx.x;
  int n0 = (bid % 12) * 128;
  int m0 = (bid / 12) * 128;
  int tid = threadIdx.x;
  int lane = tid & 63, wid = tid >> 6;
  int wm = wid >> 1, wn = wid & 1;
  int g = lane >> 4, l15 = lane & 15;

  i32x4 acc[4][4] = {};
  for (int kc = 0; kc < 512; kc += 64) {
    __syncthreads();
#pragma unroll
    for (int p = 0; p < 4; p++) {
      int idx = p*256 + tid;
      int mat = idx >> 9;
      int i2  = idx & 511;
      int r   = i2 >> 2;
      int c16 = (i2 & 3) << 4;
      const i8* src = mat ? qwT8 : qx8;
      int base = mat ? n0 : m0;
      uint4 val = *(const uint4*)&src[(size_t)(base + r)*512 + kc + c16];
      if (mat) *(uint4*)&ws[r][c16] = val;
      else     *(uint4*)&xs[r][c16] = val;
    }
    __syncthreads();
    i32x4 a[4], b[4];
#pragma unroll
    for (int t = 0; t < 4; t++) {
      a[t] = *(const i32x4*)&xs[wm*64 + t*16 + l15][g*16];
      b[t] = *(const i32x4*)&ws[wn*64 + t*16 + l15][g*16];
    }
#pragma unroll
    for (int i = 0; i < 4; i++)
#pragma unroll
      for (int j = 0; j < 4; j++)
        acc[i][j] = mfma_i8(a[i], b[j], acc[i][j]);
  }
  const int t4idx = (bid / 12) * 2 + wm;
#pragma unroll
  for (int i = 0; i < 4; i++)
#pragma unroll
    for (int j = 0; j < 4; j++) {
      u32 d = 0;
#pragma unroll
      for (int r = 0; r < 4; r++)
        d |= (u32)(iclip8(rhe(acc[i][j][r], 10)) & 0xFF) << (8*r);
      int col1536 = n0 + wn*64 + j*16 + l15;
      int gate = col1536 >> 9;
      int hcol = col1536 & 511;
      qwx2[((((size_t)t4idx*4 + i)*512 + hcol)*4 + g)*3 + gate] = d;
    }
}

// ---------------- phase 2: 512-step recurrence, fan-in-1 pairs --------------
// 8 WGs x 512 threads: (bg = bid>>1, half = bid&1) owns 16 batch rows and the
// K-half [half*256, half*256+256). Own K-half: R B-frags in registers, A via
// swizzled LDS image (intra-WG). Partner K-half: A via LLC tagged ring (ONE
// producer), B streamed from L2 (hot). Own-MFMA phase covers partner publish
// latency. Gates fully in-lane. ONE barrier per step.
__global__ __launch_bounds__(512, 1) void k2_gru(const float* __restrict__ h0,
                                                 const u32* __restrict__ qwx2,
                                                 const i8*  __restrict__ qrT8,
                                                 const int* __restrict__ qbx,
                                                 const int* __restrict__ qbr,
                                                 const int* __restrict__ lut,
                                                 u32* __restrict__ ring,
                                                 float* __restrict__ out){
  const int bid  = blockIdx.x;
  const int bg   = bid >> 1, half = bid & 1;
  const int tid  = threadIdx.x;
  const int lane = tid & 63, w = tid >> 6;        // 8 waves
  const int g = lane >> 4, l15 = lane & 15;

  __shared__ int l_sig[256], l_th[256];
  __shared__ __align__(16) i8 hl[2][4096];        // own-half h image, parity

  if (tid < 256) { l_sig[tid] = lut[tid]; l_th[tid] = lut[256 + tid]; }

  const int hc0 = half*256 + w*32;                // wave's first h-col (global)

  // ---- own-K-half R fragments (registers): 6 n-tiles x 4 k-chunks = 96 VGPR
  i32x4 rf[6][4];
  const i8* pBp[6];                               // partner-half B base ptrs
#pragma unroll
  for (int nt = 0; nt < 6; nt++) {
    int colR = (nt >> 1)*512 + hc0 + (nt & 1)*16 + l15;
    const i8* rp = qrT8 + (size_t)colR*512;
#pragma unroll
    for (int j = 0; j < 4; j++)
      rf[nt][j] = *(const i32x4*)(rp + (half*4 + j)*64 + g*16);
    pBp[nt] = rp + (1 - half)*256 + g*16;
  }

  // ---- biases for lane's 2 cols (s = 0,1)
  int bxv[3][2], brv[3][2];
#pragma unroll
  for (int s = 0; s < 2; s++) {
    int col = hc0 + s*16 + l15;
#pragma unroll
    for (int gate = 0; gate < 3; gate++) {
      bxv[gate][s] = qbx[gate*512 + col];
      brv[gate][s] = qbr[gate*512 + col];
    }
  }

  // ---- h state: rows 4g+r, cols hc0 + 16s + l15
  int qh[4][2];
#pragma unroll
  for (int r = 0; r < 4; r++)
#pragma unroll
    for (int s = 0; s < 2; s++)
      qh[r][s] = qi8(h0[(size_t)(bg*16 + 4*g + r)*512 + hc0 + s*16 + l15], 128.f);

  const u64 ringb = (u64)ring;
  const int mywg = bg*2 + half, pwg = bg*2 + (1 - half);

  // publish geometry (constant per lane)
  const int s_mine = lane & 1;                    // even lane publishes s=0
  const int jh = l15 >> 1;                        // colpair within 8
  const int cp_rel = w*16 + 8*s_mine + jh;
  const int kcr = cp_rel >> 5, cp5 = cp_rel & 31;
  const int g_c = cp5 >> 3, jj = cp5 & 7;
  const int brel = w*2 + s_mine;                  // 16-col block in own image

  auto publish = [&](int tag, int slot, int par){
    u32 my0 = 0, my1 = 0;
#pragma unroll
    for (int r = 0; r < 4; r++) {
      my0 |= (u32)(qh[r][0] & 0xFF) << (8*r);
      my1 |= (u32)(qh[r][1] & 0xFF) << (8*r);
    }
    u32 nb0 = (u32)__shfl_xor((int)my0, 1, 64);
    u32 nb1 = (u32)__shfl_xor((int)my1, 1, 64);
    u32 lo = s_mine ? nb1 : my0;                  // even col byte
    u32 hi = s_mine ? my1 : nb0;                  // odd col byte
    u64 base = ringb + (u64)((slot*8 + mywg) * 8192);
#pragma unroll
    for (int r = 0; r < 4; r++) {
      int row = 4*g + r;
      u32 d = ((lo >> (8*r)) & 0xFF) | (((hi >> (8*r)) & 0xFF) << 8);
      *(u16*)&hl[par][row*256 + ((brel ^ (row & 7)) << 4) + 2*jh] = (u16)d;
      int widx = ((kcr*4 + g_c)*16 + row)*8 + jj;
      st_llc((u32*)(base + (u64)widx*4), d | ((u32)tag << 16));
    }
  };

  // ---- publish h(0): ring slot 0 tag 1, LDS parity 0
  publish(1, 0, 0);

  // ---- Wx preload for t = 0: 6 dwords (2 cols x 3 gates), rows 4g+0..3
  u32 wxd[6];
#pragma unroll
  for (int s = 0; s < 2; s++) {
    const u32* p = qwx2 + ((((size_t)0*4 + bg)*512 + (hc0 + s*16 + l15))*4 + g)*3;
    wxd[s*3 + 0] = p[0]; wxd[s*3 + 1] = p[1]; wxd[s*3 + 2] = p[2];
  }

  const u64 laneoff = (u64)((g*16 + l15) * 32);   // within partner image

  for (int t = 0; t < NSTEP; t++) {
    const int par = t & 1;
    __syncthreads();                              // own image parity ready

    // ---- own-half MFMAs (A from LDS, B from registers)
    i32x4 acc[6] = {};
#pragma unroll
    for (int j = 0; j < 4; j++) {
      i32x4 A = *(const i32x4*)&hl[par][l15*256 + (((j*4 + g) ^ (l15 & 7)) << 4)];
#pragma unroll
      for (int nt = 0; nt < 6; nt++)
        acc[nt] = mfma_i8(A, rf[nt][j], acc[nt]);
    }

    // ---- poll partner image (tag t+1, slot t&1): 4 chunks x 8 words
    const u32 want2 = (u32)(t + 1) | ((u32)(t + 1) << 16);
    u64 a0 = ringb + (u64)((par*8 + pwg) * 8192) + laneoff;
    u64 a1 = a0 + 4096;
    uint4 q0, q1, q2, q3, q4, q5, q6, q7;
    int rounds = 0;
    for (;;) {
      asm volatile(
        "global_load_dwordx4 %0, %8, off sc0 sc1\n\t"
        "global_load_dwordx4 %1, %8, off offset:16 sc0 sc1\n\t"
        "global_load_dwordx4 %2, %8, off offset:2048 sc0 sc1\n\t"
        "global_load_dwordx4 %3, %8, off offset:2064 sc0 sc1\n\t"
        "global_load_dwordx4 %4, %9, off sc0 sc1\n\t"
        "global_load_dwordx4 %5, %9, off offset:16 sc0 sc1\n\t"
        "global_load_dwordx4 %6, %9, off offset:2048 sc0 sc1\n\t"
        "global_load_dwordx4 %7, %9, off offset:2064 sc0 sc1\n\t"
        "s_waitcnt vmcnt(0)"
        : "=&v"(q0), "=&v"(q1), "=&v"(q2), "=&v"(q3),
          "=&v"(q4), "=&v"(q5), "=&v"(q6), "=&v"(q7)
        : "v"(a0), "v"(a1)
        : "memory");
      u32 diff = 0u;
#define TCHK(P) \
      diff |= __builtin_amdgcn_perm((P).y, (P).x, 0x07060302u) ^ want2; \
      diff |= __builtin_amdgcn_perm((P).w, (P).z, 0x07060302u) ^ want2;
      TCHK(q0) TCHK(q1) TCHK(q2) TCHK(q3) TCHK(q4) TCHK(q5) TCHK(q6) TCHK(q7)
#undef TCHK
      if (diff == 0u) break;
      if (++rounds > (1 << 22)) break;            // hang-prevention only
      __builtin_amdgcn_s_sleep(1);
    }

    // ---- Wx prefetch for t+1 (hides under partner MFMAs)
    u32 nx[6] = {0, 0, 0, 0, 0, 0};
    if (t < NSTEP - 1) {
#pragma unroll
      for (int s = 0; s < 2; s++) {
        const u32* p = qwx2 + ((((size_t)(t + 1)*4 + bg)*512 + (hc0 + s*16 + l15))*4 + g)*3;
        nx[s*3 + 0] = p[0]; nx[s*3 + 1] = p[1]; nx[s*3 + 2] = p[2];
      }
    }

    // ---- partner A-frags (strip tags)
    i32x4 Ap[4];
#define PACKA(A, Pa, Pb) \
    A.x = (int)__builtin_amdgcn_perm((Pa).y, (Pa).x, 0x05040100u); \
    A.y = (int)__builtin_amdgcn_perm((Pa).w, (Pa).z, 0x05040100u); \
    A.z = (int)__builtin_amdgcn_perm((Pb).y, (Pb).x, 0x05040100u); \
    A.w = (int)__builtin_amdgcn_perm((Pb).w, (Pb).z, 0x05040100u);
    PACKA(Ap[0], q0, q1) PACKA(Ap[1], q2, q3)
    PACKA(Ap[2], q4, q5) PACKA(Ap[3], q6, q7)
#undef PACKA

    // ---- partner-half MFMAs, B streamed from L2 in 2 batches (VGPR control)
#pragma unroll
    for (int b = 0; b < 2; b++) {
      i32x4 sb[6][2];
#pragma unroll
      for (int nt = 0; nt < 6; nt++) {
        sb[nt][0] = *(const i32x4*)(pBp[nt] + (b*2 + 0)*64);
        sb[nt][1] = *(const i32x4*)(pBp[nt] + (b*2 + 1)*64);
      }
#pragma unroll
      for (int jb = 0; jb < 2; jb++)
#pragma unroll
        for (int nt = 0; nt < 6; nt++)
          acc[nt] = mfma_i8(Ap[b*2 + jb], sb[nt][jb], acc[nt]);
    }

    // ---- gates, fully in-lane (z = acc[s], r = acc[2+s], n = acc[4+s])
#pragma unroll
    for (int s = 0; s < 2; s++) {
#pragma unroll
      for (int r = 0; r < 4; r++) {
        int rz = iclip8(rhe(iclip8(rhe(acc[0 + s][r], 13))*16 + brv[0][s], 4));
        int rr = iclip8(rhe(iclip8(rhe(acc[2 + s][r], 13))*16 + brv[1][s], 4));
        int rg = iclip8(rhe(iclip8(rhe(acc[4 + s][r], 13))*16 + brv[2][s], 4));
        int wz = (int)(i8)((wxd[s*3 + 0] >> (8*r)) & 0xFF);
        int wr = (int)(i8)((wxd[s*3 + 1] >> (8*r)) & 0xFF);
        int wg = (int)(i8)((wxd[s*3 + 2] >> (8*r)) & 0xFF);
        int uz  = l_sig[128 + iclip8(rhe(16*(wz + rz) + bxv[0][s], 5))];
        int ur  = l_sig[128 + iclip8(rhe(16*(wr + rr) + bxv[1][s], 5))];
        int qrh = iclip8(rhe(ur * rg, 8));
        int qg  = l_th[128 + iclip8(rhe(16*(wg + qrh) + bxv[2][s], 5))];
        int qold = iclip8(rhe(uz * qh[r][s], 8));
        int qnew = iclip8(rhe((256 - uz) * qg, 8));
        qh[r][s] = iclip8(qold + qnew);
      }
    }

    // ---- publish h(t+1): ring slot (t+1)&1 tag t+2, LDS parity (t+1)&1
    publish(t + 2, (t + 1) & 1, (t + 1) & 1);

    // ---- out stores (coalesced 64B per 16-lane group)
#pragma unroll
    for (int s = 0; s < 2; s++)
#pragma unroll
      for (int r = 0; r < 4; r++)
        out[((size_t)t*64 + bg*16 + 4*g + r)*512 + hc0 + s*16 + l15] =
            qh[r][s] * 0.0078125f;

#pragma unroll
    for (int e = 0; e < 6; e++) wxd[e] = nx[e];
  }
}

// ---------------- launch ----------------
extern "C" void kernel_launch(void* const* d_in, const int* in_sizes, int n_in,
                              void* d_out, int out_size, void* d_ws, size_t ws_size,
                              hipStream_t stream) {
  const float* x  = (const float*)d_in[0];
  const float* h0 = (const float*)d_in[1];
  const float* W  = (const float*)d_in[2];
  const float* R  = (const float*)d_in[3];
  const float* bx = (const float*)d_in[4];
  const float* br = (const float*)d_in[5];
  float* out = (float*)d_out;

  if (ws_size < WS_NEED) return;   // insufficient scratch; fail loudly

  char* ws = (char*)d_ws;
  i8*  qx8   = (i8*) (ws + OFF_QX8);
  i8*  qwT8  = (i8*) (ws + OFF_QWT8);
  i8*  qrT8  = (i8*) (ws + OFF_QRT8);
  u32* qwx2  = (u32*)(ws + OFF_QWX2);
  int* qbx   = (int*)(ws + OFF_QBX);
  int* qbr   = (int*)(ws + OFF_QBR);
  int* lut   = (int*)(ws + OFF_LUT);
  u32* ring  = (u32*)(ws + OFF_RING);

  k0a_qx  <<<2048, 256, 0, stream>>>(x, (u32*)qx8, 32768*512/4);
  k0b_qwr <<<6144, 256, 0, stream>>>(W, R, qwT8, qrT8);
  k0c_misc<<<16,   256, 0, stream>>>(bx, br, qbx, qbr, lut, ring);
  k1_gemm_wx<<<3072, 256, 0, stream>>>(qx8, qwT8, qwx2);
  k2_gru  <<<8, 512, 0, stream>>>(h0, qwx2, qrT8, qbx, qbr, lut, ring, out);
}